// Round 6
// baseline (34.464 us; speedup 1.0000x reference)
//
#include <hip/hip_runtime.h>

namespace {

constexpr float ETA_C = 1.5f;
constexpr float PI_F  = 3.14159265358979323846f;
constexpr int   BLOCK = 256;

typedef float f32x4 __attribute__((ext_vector_type(4)));

__device__ __forceinline__ float fast_rcp(float x)  { return __builtin_amdgcn_rcpf(x); }
__device__ __forceinline__ float fast_sqrt(float x) { return __builtin_amdgcn_sqrtf(x); }
__device__ __forceinline__ float fast_rsq(float x)  { return __builtin_amdgcn_rsqf(x); }

__device__ __forceinline__ float schlick_w(float c) {
    float m = fminf(fmaxf(1.0f - c, 0.0f), 1.0f);
    float m2 = m * m;
    return m2 * m2 * m;  // m^5
}

// One group = 4 points worth of inputs (12 f32x4 regs payload).
struct Grp {
    f32x4 dv, av, rv, mv, tv;
    f32x4 n0, n1, n2, v0, v1, v2, s0, s1, s2, b0, b1, b2;
};

// Compute 4 points -> 3 output f32x4 (xyzx | yzxy | zxyz packing).
__device__ __forceinline__ void process4(const Grp& g, float light,
                                         f32x4& o0, f32x4& o1, f32x4& o2) {
    const float dist[4] = {g.dv.x, g.dv.y, g.dv.z, g.dv.w};
    const float anv[4]  = {g.av.x, g.av.y, g.av.z, g.av.w};
    const float rgv[4]  = {g.rv.x, g.rv.y, g.rv.z, g.rv.w};
    const float mtv[4]  = {g.mv.x, g.mv.y, g.mv.z, g.mv.w};
    const float ttv[4]  = {g.tv.x, g.tv.y, g.tv.z, g.tv.w};

    const float nx[4] = {g.n0.x, g.n0.w, g.n1.z, g.n2.y};
    const float ny[4] = {g.n0.y, g.n1.x, g.n1.w, g.n2.z};
    const float nz[4] = {g.n0.z, g.n1.y, g.n2.x, g.n2.w};
    const float vx[4] = {g.v0.x, g.v0.w, g.v1.z, g.v2.y};
    const float vy[4] = {g.v0.y, g.v1.x, g.v1.w, g.v2.z};
    const float vz[4] = {g.v0.z, g.v1.y, g.v2.x, g.v2.w};
    const float sx[4] = {g.s0.x, g.s0.w, g.s1.z, g.s2.y};
    const float sy[4] = {g.s0.y, g.s1.x, g.s1.w, g.s2.z};
    const float sz[4] = {g.s0.z, g.s1.y, g.s2.x, g.s2.w};
    const float bx[4] = {g.b0.x, g.b0.w, g.b1.z, g.b2.y};
    const float by[4] = {g.b0.y, g.b1.x, g.b1.w, g.b2.z};
    const float bz[4] = {g.b0.z, g.b1.y, g.b2.x, g.b2.w};

    float ox[4], oy[4], oz[4];

#pragma unroll
    for (int j = 0; j < 4; ++j) {
        const float cosv = nx[j] * vx[j] + ny[j] * vy[j] + nz[j] * vz[j];
        const float anis  = fmaxf(anv[j], 1e-5f);
        const float rough = fmaxf(rgv[j], 1e-5f);
        const float met   = fmaxf(mtv[j], 1e-5f);
        const float tint  = fmaxf(ttv[j], 1e-6f);
        const float sa[3] = {fmaxf(sx[j], 1e-5f), fmaxf(sy[j], 1e-5f), fmaxf(sz[j], 1e-5f)};
        const float da[3] = {fmaxf(bx[j], 1e-5f), fmaxf(by[j], 1e-5f), fmaxf(bz[j], 1e-5f)};

        const float c2 = cosv * cosv;
        const float ci = fabsf(cosv);

        // anisotropic GGX alphas
        const float r2 = fast_sqrt(rough);
        const float w  = 1.0f - 0.9f * anis;
        const float alpha_u = fmaxf(r2 * fast_rsq(w),  1e-4f);
        const float alpha_v = fmaxf(r2 * fast_sqrt(w), 1e-4f);

        // fresnel_dielectric(cos, 1.5)
        const float scale  = (cosv > 0.0f) ? (1.0f / ETA_C) : ETA_C;
        const float ct_sqr = 1.0f - (1.0f - c2) * scale * scale;
        const float ctf = fast_sqrt(ct_sqr);
        const float rs  = (ci - ETA_C * ctf) * fast_rcp(ci + ETA_C * ctf);
        const float rp  = (ETA_C * ci - ctf) * fast_rcp(ETA_C * ci + ctf);
        const float f_die = 0.5f * (rs * rs + rp * rp);

        // D term (module passes eta as alpha; preserved)
        const float a2 = ETA_C * ETA_C;
        const float root_d = c2 + (1.0f - c2) * (1.0f / (a2 + 1e-10f));
        const float d_den  = PI_F * a2 * root_d * root_d + 1e-10f;

        // G term
        const float sin_t = fast_sqrt(fmaxf(1.0f - c2, 0.0f));
        const float tan_t = sin_t * fast_rcp(cosv + 1e-10f);
        const float ru  = alpha_u * tan_t;
        const float rw  = alpha_v * tan_t;
        const float g_u = 2.0f * fast_rcp(1.0f + fast_sqrt(ru * ru + 1.0f));
        const float g_v = 2.0f * fast_rcp(1.0f + fast_sqrt(rw * rw + 1.0f));
        const float g_spec = g_u * g_v;

        const float lum = light * fast_rcp(dist[j] * dist[j] + 1e-10f);
        const float eta_it = (cosv > 0.0f) ? ETA_C : (1.0f / ETA_C);

        // calc_schlick (eta clamped to 0.99999 -> always val_neq1 branch)
        const float eti2 = 0.99999f * 0.99999f;
        const float ct_s = fast_sqrt(1.0f - (1.0f - c2) * eti2);
        const float sw_ct = schlick_w(ct_s);

        float f0s = (eta_it - 1.0f) * fast_rcp(eta_it + 1.0f);
        f0s = f0s * f0s;

        // diffuse + retro-reflection
        const float fw = schlick_w(ci);
        float f_diff = 1.0f - 0.5f * fw;
        f_diff *= f_diff;
        const float alpha_d = 1.0f - rough;
        const float rr = 2.0f * alpha_d * c2;
        const float f_retro = rr * (2.0f * fw + fw * fw * (rr - 1.0f));
        const float one_m_met = 1.0f - met;
        const float diff_com = one_m_met * ci * (1.0f / PI_F) * (f_diff + f_retro);

        const float spec_com = g_spec * fast_rcp(d_den * 4.0f * ci);

        const float rcp_lum = fast_rcp(lum);
        const float lum_pos = (lum > 0.0f) ? 1.0f : 0.0f;

        float o[3];
#pragma unroll
        for (int k = 0; k < 3; ++k) {
            float fs = (sw_ct * (1.0f - sa[k]) + sa[k]) * met;
            const float c_tint = lum_pos * (sa[k] * rcp_lum) + (1.0f - lum_pos);
            const float f0t = c_tint * f0s;
            fs += one_m_met * tint * (sw_ct * (1.0f - f0t) + f0t);
            const float f_princ = one_m_met * (1.0f - tint) * (f_die * sa[k]) + fs;
            o[k] = f_princ * spec_com + diff_com * da[k];
        }
        ox[j] = o[0]; oy[j] = o[1]; oz[j] = o[2];
    }

    o0 = (f32x4){ox[0], oy[0], oz[0], ox[1]};
    o1 = (f32x4){oy[1], oz[1], ox[2], oy[2]};
    o2 = (f32x4){oz[2], ox[3], oy[3], oz[3]};
}

#define LOAD_GRP(g, idx)                                                      \
    do {                                                                      \
        const int _i = (idx);                                                 \
        g.dv = reinterpret_cast<const f32x4*>(dist_p)[_i];                    \
        g.av = reinterpret_cast<const f32x4*>(anis_p)[_i];                    \
        g.rv = reinterpret_cast<const f32x4*>(rough_p)[_i];                   \
        g.mv = reinterpret_cast<const f32x4*>(met_p)[_i];                     \
        g.tv = reinterpret_cast<const f32x4*>(tint_p)[_i];                    \
        const f32x4* _n = reinterpret_cast<const f32x4*>(norm_p) + 3 * _i;    \
        g.n0 = _n[0]; g.n1 = _n[1]; g.n2 = _n[2];                             \
        const f32x4* _v = reinterpret_cast<const f32x4*>(view_p) + 3 * _i;    \
        g.v0 = _v[0]; g.v1 = _v[1]; g.v2 = _v[2];                             \
        const f32x4* _s = reinterpret_cast<const f32x4*>(salb_p) + 3 * _i;    \
        g.s0 = _s[0]; g.s1 = _s[1]; g.s2 = _s[2];                             \
        const f32x4* _b = reinterpret_cast<const f32x4*>(dalb_p) + 3 * _i;    \
        g.b0 = _b[0]; g.b1 = _b[1]; g.b2 = _b[2];                             \
    } while (0)

// 8 points/thread in two coalesced halves (group A: f32x4 idx t, group B:
// idx t+T) -> 24 loads in flight across the fence. (256,3): VGPR cap ~168.
__global__ __launch_bounds__(BLOCK, 3) void renderer_kernel(
    const float* __restrict__ light_p,
    const float* __restrict__ dist_p,
    const float* __restrict__ norm_p,
    const float* __restrict__ view_p,
    const float* __restrict__ anis_p,
    const float* __restrict__ rough_p,
    const float* __restrict__ met_p,
    const float* __restrict__ tint_p,
    const float* __restrict__ salb_p,
    const float* __restrict__ dalb_p,
    float* __restrict__ out_p,
    int n_pts)
{
    const int T = n_pts >> 3;                         // threads total (f32x4 groups per half)
    const int t = blockIdx.x * BLOCK + threadIdx.x;
    if (t >= T) return;

    Grp ga, gb;
    LOAD_GRP(ga, t);
    LOAD_GRP(gb, t + T);
    const float light = light_p[0];

    // Fence: all 24 vmem loads issued before any compute (R5: this is the
    // proven lever; one exposed latency per wave, VGPR forced up).
    __builtin_amdgcn_sched_barrier(0);

    f32x4 a0, a1, a2;
    process4(ga, light, a0, a1, a2);
    {
        f32x4* out4 = reinterpret_cast<f32x4*>(out_p) + 3 * t;
        __builtin_nontemporal_store(a0, out4 + 0);
        __builtin_nontemporal_store(a1, out4 + 1);
        __builtin_nontemporal_store(a2, out4 + 2);
    }
    // Fence: keep B's compute from being interleaved into A's (register
    // pressure control; B payload alone is 48 VGPRs).
    __builtin_amdgcn_sched_barrier(0);

    f32x4 b0, b1, b2;
    process4(gb, light, b0, b1, b2);
    {
        f32x4* out4 = reinterpret_cast<f32x4*>(out_p) + 3 * (t + T);
        __builtin_nontemporal_store(b0, out4 + 0);
        __builtin_nontemporal_store(b1, out4 + 1);
        __builtin_nontemporal_store(b2, out4 + 2);
    }
}

}  // namespace

extern "C" void kernel_launch(void* const* d_in, const int* in_sizes, int n_in,
                              void* d_out, int out_size, void* d_ws, size_t ws_size,
                              hipStream_t stream) {
    (void)n_in; (void)out_size; (void)d_ws; (void)ws_size;
    // input order per setup_inputs():
    // 0 light(1) 1 distance(N) 2 normal(N,3) 3 viewdir(N,3) 4 anisotropic(N)
    // 5 specular_roughness(N) 6 metallic(N) 7 clearcoat(N, UNUSED)
    // 8 spec_tint(N) 9 specular_albedo(N,3) 10 diffuse_albedo(N,3)
    const float* light_p = (const float*)d_in[0];
    const float* dist_p  = (const float*)d_in[1];
    const float* norm_p  = (const float*)d_in[2];
    const float* view_p  = (const float*)d_in[3];
    const float* anis_p  = (const float*)d_in[4];
    const float* rough_p = (const float*)d_in[5];
    const float* met_p   = (const float*)d_in[6];
    const float* tint_p  = (const float*)d_in[8];
    const float* salb_p  = (const float*)d_in[9];
    const float* dalb_p  = (const float*)d_in[10];
    float* out_p = (float*)d_out;

    const int n_pts = in_sizes[1];          // N = 2,097,152 (divisible by 8*BLOCK)
    const int n_thr = n_pts / 8;            // 262,144 threads
    const int grid  = (n_thr + BLOCK - 1) / BLOCK;   // 1024 blocks

    renderer_kernel<<<grid, BLOCK, 0, stream>>>(
        light_p, dist_p, norm_p, view_p, anis_p, rough_p, met_p, tint_p,
        salb_p, dalb_p, out_p, n_pts);
}

// Round 7
// 29.753 us; speedup vs baseline: 1.1583x; 1.1583x over previous
//
#include <hip/hip_runtime.h>

namespace {

constexpr float ETA_C = 1.5f;
constexpr float PI_F  = 3.14159265358979323846f;
constexpr int   BLOCK = 256;

typedef float f32x2 __attribute__((ext_vector_type(2)));

__device__ __forceinline__ float fast_rcp(float x)  { return __builtin_amdgcn_rcpf(x); }
__device__ __forceinline__ float fast_sqrt(float x) { return __builtin_amdgcn_sqrtf(x); }
__device__ __forceinline__ float fast_rsq(float x)  { return __builtin_amdgcn_rsqf(x); }

__device__ __forceinline__ float schlick_w(float c) {
    float m = fminf(fmaxf(1.0f - c, 0.0f), 1.0f);
    float m2 = m * m;
    return m2 * m2 * m;  // m^5
}

// Compute one point. All inputs scalar; outputs 3 floats.
__device__ __forceinline__ void process1(
    float light, float dist, float anv, float rgv, float mtv, float ttv,
    float nx, float ny, float nz, float vx, float vy, float vz,
    float sxx, float syy, float szz, float bxx, float byy, float bzz,
    float& o0, float& o1, float& o2)
{
    const float cosv = nx * vx + ny * vy + nz * vz;
    const float anis  = fmaxf(anv, 1e-5f);
    const float rough = fmaxf(rgv, 1e-5f);
    const float met   = fmaxf(mtv, 1e-5f);
    const float tint  = fmaxf(ttv, 1e-6f);
    const float sa[3] = {fmaxf(sxx, 1e-5f), fmaxf(syy, 1e-5f), fmaxf(szz, 1e-5f)};
    const float da[3] = {fmaxf(bxx, 1e-5f), fmaxf(byy, 1e-5f), fmaxf(bzz, 1e-5f)};

    const float c2 = cosv * cosv;
    const float ci = fabsf(cosv);

    // anisotropic GGX alphas
    const float r2 = fast_sqrt(rough);
    const float w  = 1.0f - 0.9f * anis;
    const float alpha_u = fmaxf(r2 * fast_rsq(w),  1e-4f);
    const float alpha_v = fmaxf(r2 * fast_sqrt(w), 1e-4f);

    // fresnel_dielectric(cos, 1.5)
    const float scale  = (cosv > 0.0f) ? (1.0f / ETA_C) : ETA_C;
    const float ct_sqr = 1.0f - (1.0f - c2) * scale * scale;
    const float ctf = fast_sqrt(ct_sqr);
    const float rs  = (ci - ETA_C * ctf) * fast_rcp(ci + ETA_C * ctf);
    const float rp  = (ETA_C * ci - ctf) * fast_rcp(ETA_C * ci + ctf);
    const float f_die = 0.5f * (rs * rs + rp * rp);

    // D term (module passes eta as alpha; preserved)
    const float a2 = ETA_C * ETA_C;
    const float root_d = c2 + (1.0f - c2) * (1.0f / (a2 + 1e-10f));
    const float d_den  = PI_F * a2 * root_d * root_d + 1e-10f;

    // G term
    const float sin_t = fast_sqrt(fmaxf(1.0f - c2, 0.0f));
    const float tan_t = sin_t * fast_rcp(cosv + 1e-10f);
    const float ru  = alpha_u * tan_t;
    const float rw  = alpha_v * tan_t;
    const float g_u = 2.0f * fast_rcp(1.0f + fast_sqrt(ru * ru + 1.0f));
    const float g_v = 2.0f * fast_rcp(1.0f + fast_sqrt(rw * rw + 1.0f));
    const float g_spec = g_u * g_v;

    const float lum = light * fast_rcp(dist * dist + 1e-10f);
    const float eta_it = (cosv > 0.0f) ? ETA_C : (1.0f / ETA_C);

    // calc_schlick (eta clamped to 0.99999 -> always val_neq1 branch)
    const float eti2 = 0.99999f * 0.99999f;
    const float ct_s = fast_sqrt(1.0f - (1.0f - c2) * eti2);
    const float sw_ct = schlick_w(ct_s);

    float f0s = (eta_it - 1.0f) * fast_rcp(eta_it + 1.0f);
    f0s = f0s * f0s;

    // diffuse + retro-reflection
    const float fw = schlick_w(ci);
    float f_diff = 1.0f - 0.5f * fw;
    f_diff *= f_diff;
    const float alpha_d = 1.0f - rough;
    const float rr = 2.0f * alpha_d * c2;
    const float f_retro = rr * (2.0f * fw + fw * fw * (rr - 1.0f));
    const float one_m_met = 1.0f - met;
    const float diff_com = one_m_met * ci * (1.0f / PI_F) * (f_diff + f_retro);

    const float spec_com = g_spec * fast_rcp(d_den * 4.0f * ci);

    const float rcp_lum = fast_rcp(lum);
    const float lum_pos = (lum > 0.0f) ? 1.0f : 0.0f;

    float o[3];
#pragma unroll
    for (int k = 0; k < 3; ++k) {
        float fs = (sw_ct * (1.0f - sa[k]) + sa[k]) * met;
        const float c_tint = lum_pos * (sa[k] * rcp_lum) + (1.0f - lum_pos);
        const float f0t = c_tint * f0s;
        fs += one_m_met * tint * (sw_ct * (1.0f - f0t) + f0t);
        const float f_princ = one_m_met * (1.0f - tint) * (f_die * sa[k]) + fs;
        o[k] = f_princ * spec_com + diff_com * da[k];
    }
    o0 = o[0]; o1 = o[1]; o2 = o[2];
}

// Max-TLP probe: 2 points/thread, 17 dwordx2 loads, fence retained.
// No launch_bounds: payload is only ~34 VGPRs, allocator can stay <=64
// -> 8 waves/SIMD; grid 4096 wg = 16 wg/CU, 2 generations of full residency.
__global__ void renderer_kernel(
    const float* __restrict__ light_p,
    const float* __restrict__ dist_p,
    const float* __restrict__ norm_p,
    const float* __restrict__ view_p,
    const float* __restrict__ anis_p,
    const float* __restrict__ rough_p,
    const float* __restrict__ met_p,
    const float* __restrict__ tint_p,
    const float* __restrict__ salb_p,
    const float* __restrict__ dalb_p,
    float* __restrict__ out_p,
    int n_pts)
{
    const int t = blockIdx.x * BLOCK + threadIdx.x;   // one thread = 2 points
    if (t * 2 >= n_pts) return;

    // ---- 17 coalesced dwordx2 loads (64 lanes x 8B = 512B contiguous) ----
    const f32x2 d2 = reinterpret_cast<const f32x2*>(dist_p)[t];
    const f32x2 a2v = reinterpret_cast<const f32x2*>(anis_p)[t];
    const f32x2 r2v = reinterpret_cast<const f32x2*>(rough_p)[t];
    const f32x2 m2 = reinterpret_cast<const f32x2*>(met_p)[t];
    const f32x2 t2 = reinterpret_cast<const f32x2*>(tint_p)[t];

    const f32x2* n2 = reinterpret_cast<const f32x2*>(norm_p) + 3 * t;
    const f32x2 n0 = n2[0], n1 = n2[1], nn2 = n2[2];
    const f32x2* v2 = reinterpret_cast<const f32x2*>(view_p) + 3 * t;
    const f32x2 v0 = v2[0], v1 = v2[1], vv2 = v2[2];
    const f32x2* s2 = reinterpret_cast<const f32x2*>(salb_p) + 3 * t;
    const f32x2 s0 = s2[0], s1 = s2[1], ss2 = s2[2];
    const f32x2* b2 = reinterpret_cast<const f32x2*>(dalb_p) + 3 * t;
    const f32x2 b0 = b2[0], b1 = b2[1], bb2 = b2[2];

    const float light = light_p[0];

    // Proven lever (R5): all loads issued before any compute.
    __builtin_amdgcn_sched_barrier(0);

    float o0a, o1a, o2a, o0b, o1b, o2b;
    // point 0: n=(n0.x,n0.y,n1.x? no) -- layout: floats[6t..6t+5] = p0.xyz,p1.xyz
    process1(light, d2.x, a2v.x, r2v.x, m2.x, t2.x,
             n0.x, n0.y, n1.x, v0.x, v0.y, v1.x,
             s0.x, s0.y, s1.x, b0.x, b0.y, b1.x,
             o0a, o1a, o2a);
    // point 1
    process1(light, d2.y, a2v.y, r2v.y, m2.y, t2.y,
             n1.y, nn2.x, nn2.y, v1.y, vv2.x, vv2.y,
             s1.y, ss2.x, ss2.y, b1.y, bb2.x, bb2.y,
             o0b, o1b, o2b);

    // 3 dwordx2 nontemporal stores (8B-aligned for all t)
    f32x2* out2 = reinterpret_cast<f32x2*>(out_p) + 3 * t;
    const f32x2 w0 = {o0a, o1a};
    const f32x2 w1 = {o2a, o0b};
    const f32x2 w2 = {o1b, o2b};
    __builtin_nontemporal_store(w0, out2 + 0);
    __builtin_nontemporal_store(w1, out2 + 1);
    __builtin_nontemporal_store(w2, out2 + 2);
}

}  // namespace

extern "C" void kernel_launch(void* const* d_in, const int* in_sizes, int n_in,
                              void* d_out, int out_size, void* d_ws, size_t ws_size,
                              hipStream_t stream) {
    (void)n_in; (void)out_size; (void)d_ws; (void)ws_size;
    // input order per setup_inputs():
    // 0 light(1) 1 distance(N) 2 normal(N,3) 3 viewdir(N,3) 4 anisotropic(N)
    // 5 specular_roughness(N) 6 metallic(N) 7 clearcoat(N, UNUSED)
    // 8 spec_tint(N) 9 specular_albedo(N,3) 10 diffuse_albedo(N,3)
    const float* light_p = (const float*)d_in[0];
    const float* dist_p  = (const float*)d_in[1];
    const float* norm_p  = (const float*)d_in[2];
    const float* view_p  = (const float*)d_in[3];
    const float* anis_p  = (const float*)d_in[4];
    const float* rough_p = (const float*)d_in[5];
    const float* met_p   = (const float*)d_in[6];
    const float* tint_p  = (const float*)d_in[8];
    const float* salb_p  = (const float*)d_in[9];
    const float* dalb_p  = (const float*)d_in[10];
    float* out_p = (float*)d_out;

    const int n_pts = in_sizes[1];          // N = 2,097,152 (divisible by 2*BLOCK)
    const int n_thr = n_pts / 2;            // 1,048,576 threads
    const int grid  = (n_thr + BLOCK - 1) / BLOCK;   // 4096 blocks

    renderer_kernel<<<grid, BLOCK, 0, stream>>>(
        light_p, dist_p, norm_p, view_p, anis_p, rough_p, met_p, tint_p,
        salb_p, dalb_p, out_p, n_pts);
}